// Round 15
// baseline (84.971 us; speedup 1.0000x reference)
//
#include <hip/hip_runtime.h>

#define G_TOT 2016
#define NGB32 63
#define HSTR 40   // hb row stride in f16 (80B, 16B-aligned rows)
#define CSTR 33   // cob row stride (f32)

typedef _Float16 f16;
typedef __attribute__((ext_vector_type(2))) _Float16 v2h;
typedef __attribute__((ext_vector_type(8))) _Float16 v8h;
typedef __attribute__((ext_vector_type(4))) float v4f;
typedef __attribute__((ext_vector_type(16))) float v16f;

__device__ __forceinline__ v2h pkrtz(float a, float b) {
    return __builtin_bit_cast(v2h, __builtin_amdgcn_cvt_pkrtz(a, b));
}

// 32x32x16 K-slot convention (A and B share it; actual HW map cancels):
// position (chunk c, lane-half hi, elem j) <-> ksh = c*16 + (j&3) + 8*(j>>2) + 4*hi
// storage slot within a 32-wide row: c*16 + hi*8 + j  (frag load = 8 contiguous f16)
__device__ __forceinline__ int kslot32(int k) {
    const int c = k >> 4, r = k & 15;
    return c * 16 + ((r >> 2) & 1) * 8 + (r & 3) + 4 * ((r >> 3) & 1);
}

// ---------------------------------------------------------------------------
// Prep: gather Y into 32x32x16-fragment-ordered f16 tables (per 32-g block).
// A1: A-op of MFMA1 (m=g=lane&31, k=ksh by slot convention).
// B2: B-op of MFMA2 (n=ksh=lane&31, k=g by gamma = MFMA1's C/D m-layout).
// ---------------------------------------------------------------------------
__global__ void vg_prep(const float* __restrict__ Y, const float* __restrict__ qw,
                        f16* __restrict__ A1buf, f16* __restrict__ B2buf) {
    const int gb = blockIdx.x;
    const int lane = threadIdx.x & 63;
    const int lo5 = lane & 31, hi = lane >> 5;
#pragma unroll
    for (int c = 0; c < 2; ++c)
#pragma unroll
        for (int j = 0; j < 8; ++j) {
            const int ksh = c * 16 + (j & 3) + 8 * (j >> 2) + 4 * hi;
            const int g = gb * 32 + lo5;
            A1buf[((gb * 2 + c) * 64 + lane) * 8 + j] =
                (ksh < 25) ? (f16)Y[ksh * G_TOT + g] : (f16)0.0f;
            const int gB = gb * 32 + c * 16 + (j & 3) + 8 * (j >> 2) + 4 * hi;
            B2buf[((gb * 2 + c) * 64 + lane) * 8 + j] =
                (lo5 < 25) ? (f16)(Y[lo5 * G_TOT + gB] * qw[gB]) : (f16)0.0f;
        }
}

// ---------------------------------------------------------------------------
// Main fused kernel: 256 threads per (n, parity); wave q=wid owns gb = q,q+4,...
// MFMA1 (32x32x16, swapped): D[g][row=c] per (spin, v-tile) -> cross elementwise
// across the 3 v-tile outputs (same lane/reg = same (c,g)) -> packed a2 is the
// A-frag of MFMA2 (32x32x16): CO[c][ksh] += sum_g cr*Yw. 4-way CO reduce in LDS.
// Phase 0b / epilogue stay on verified 16x16x32.
// ---------------------------------------------------------------------------
template <bool USE_WS>
__global__ __launch_bounds__(256, 2)
void vg_main(const float* __restrict__ x1, const float* __restrict__ x2,
             const float* __restrict__ W1s, const float* __restrict__ W2s,
             const float* __restrict__ Wouts, const float* __restrict__ Y,
             const float* __restrict__ qw,
             const f16* __restrict__ A1buf, const f16* __restrict__ B2buf,
             float* __restrict__ out) {
    __shared__ __align__(16) char smem[15360];
    f16* hb = (f16*)smem;        // [2 spin][96 row][HSTR] f16 (phase 0)
    float* cob = (float*)smem;   // [96][CSTR] f32 (reduce/epilogue; aliased)

    const int bid = blockIdx.x;
    const int n = bid / 3, p = bid % 3;
    const int tid = threadIdx.x;
    const int wid = tid >> 6;
    const int lane = tid & 63;
    const int lhi = lane >> 4, llo = lane & 15;   // 16-lane groups (phase0b/epilogue)
    const int lo5 = lane & 31, hi5 = lane >> 5;   // 32-lane groups (main loop)

    const v4f zero4 = {0.0f, 0.0f, 0.0f, 0.0f};
    v16f zero16;
#pragma unroll
    for (int i = 0; i < 16; ++i) zero16[i] = 0.0f;

    // ---- phase 0a: zero hb
    for (int i = tid; i < 3840; i += 256) ((float*)smem)[i] = 0.0f;
    __syncthreads();

    // ---- phase 0b (16x16x32 MFMA, all 4 waves): wave (s, ct) quarter of mix.
    {
        const int s = wid & 1, ct = wid >> 1;
        const float* xs = (s ? x2 : x1) + n * 2400;
        const float* Wp = (s ? W2s : W1s) + p * 5120;
        v8h bf[5];
#pragma unroll
        for (int l = 0; l < 5; ++l)
#pragma unroll
            for (int j = 0; j < 8; ++j) {
                const int f = (j < 4) ? (lhi * 4 + j) : (16 + lhi * 4 + (j - 4));
                bf[l][j] = (f16)Wp[l * 1024 + f * 32 + ct * 16 + llo];
            }
        f16* hbs = hb + s * 96 * HSTR;
#pragma unroll
        for (int vt = 0; vt < 5; ++vt) {
            v8h af;
            const int vkb = vt * 16 + llo;
#pragma unroll
            for (int j = 0; j < 8; ++j) {
                const int f = (j < 4) ? (lhi * 4 + j) : (16 + lhi * 4 + (j - 4));
                af[j] = (vkb < 75) ? (f16)xs[f * 75 + vkb] : (f16)0.0f;
            }
            v4f D[5];
#pragma unroll
            for (int l = 0; l < 5; ++l)
                D[l] = __builtin_amdgcn_mfma_f32_16x16x32_f16(af, bf[l], zero4, 0, 0, 0);
#pragma unroll
            for (int j = 0; j < 4; ++j) {
                const int vk = vt * 16 + lhi * 4 + j;
                if (vk < 75) {
                    const int v = (vk >= 50) ? 2 : ((vk >= 25) ? 1 : 0);
                    const int k = vk - v * 25;
                    const float val = (k < 1) ? D[0][j]
                                    : (k < 4) ? D[1][j]
                                    : (k < 9) ? D[2][j]
                                    : (k < 16) ? D[3][j]
                                    : D[4][j];
                    hbs[(v * 32 + ct * 16 + llo) * HSTR + kslot32(k)] = (f16)val;
                }
            }
        }
    }
    __syncthreads();

    // ---- hoist h fragments (B-op of MFMA1, 32x32): [spin][vtile][chunk], 48 VGPR
    v8h hfr[2][3][2];
#pragma unroll
    for (int s = 0; s < 2; ++s)
#pragma unroll
        for (int vt = 0; vt < 3; ++vt)
#pragma unroll
            for (int c = 0; c < 2; ++c)
                hfr[s][vt][c] = *(const v8h*)&hb[s * 96 * HSTR + (vt * 32 + lo5) * HSTR
                                                + c * 16 + hi5 * 8];

    v16f coacc[3];
#pragma unroll
    for (int vt = 0; vt < 3; ++vt) coacc[vt] = zero16;

    union A2U { v2h p[8]; struct { v8h lo, hi; } w; };

    // one gb: MFMA1 x6 (x2 K-chunks) -> cross -> MFMA2 x6
    auto body = [&](const v8h& a1c0, const v8h& a1c1, const v8h& b2c0, const v8h& b2c1) {
        v16f agg[2][3];
#pragma unroll
        for (int s = 0; s < 2; ++s)
#pragma unroll
            for (int vt = 0; vt < 3; ++vt) {
                v16f t = __builtin_amdgcn_mfma_f32_32x32x16_f16(a1c0, hfr[s][vt][0], zero16, 0, 0, 0);
                agg[s][vt] = __builtin_amdgcn_mfma_f32_32x32x16_f16(a1c1, hfr[s][vt][1], t, 0, 0, 0);
            }
        A2U a2[3];
#pragma unroll
        for (int rp = 0; rp < 8; ++rp) {
            const v2h g10 = pkrtz(agg[0][0][2 * rp], agg[0][0][2 * rp + 1]);
            const v2h g11 = pkrtz(agg[0][1][2 * rp], agg[0][1][2 * rp + 1]);
            const v2h g12 = pkrtz(agg[0][2][2 * rp], agg[0][2][2 * rp + 1]);
            const v2h g20 = pkrtz(agg[1][0][2 * rp], agg[1][0][2 * rp + 1]);
            const v2h g21 = pkrtz(agg[1][1][2 * rp], agg[1][1][2 * rp + 1]);
            const v2h g22 = pkrtz(agg[1][2][2 * rp], agg[1][2][2 * rp + 1]);
            a2[0].p[rp] = g11 * g22 - g12 * g21;
            a2[1].p[rp] = g12 * g20 - g10 * g22;
            a2[2].p[rp] = g10 * g21 - g11 * g20;
        }
#pragma unroll
        for (int vt = 0; vt < 3; ++vt) {
            coacc[vt] = __builtin_amdgcn_mfma_f32_32x32x16_f16(a2[vt].w.lo, b2c0, coacc[vt], 0, 0, 0);
            coacc[vt] = __builtin_amdgcn_mfma_f32_32x32x16_f16(a2[vt].w.hi, b2c1, coacc[vt], 0, 0, 0);
        }
    };

    // ---- main loop: wave q = wid walks gb = q, q+4, ...
    if constexpr (USE_WS) {
        const v8h* a1b = (const v8h*)A1buf + lane;   // [gb][chunk][lane], 128 v8h per gb
        const v8h* b2b = (const v8h*)B2buf + lane;
        for (int gb = wid; gb < NGB32; gb += 4) {
            const v8h a1c0 = a1b[gb * 128];
            const v8h a1c1 = a1b[gb * 128 + 64];
            const v8h b2c0 = b2b[gb * 128];
            const v8h b2c1 = b2b[gb * 128 + 64];
            body(a1c0, a1c1, b2c0, b2c1);
        }
    } else {
        for (int gb = wid; gb < NGB32; gb += 4) {
            v8h a1c0, a1c1, b2c0, b2c1;
#pragma unroll
            for (int c = 0; c < 2; ++c)
#pragma unroll
                for (int j = 0; j < 8; ++j) {
                    const int ksh = c * 16 + (j & 3) + 8 * (j >> 2) + 4 * hi5;
                    const f16 av = (ksh < 25) ? (f16)Y[ksh * G_TOT + gb * 32 + lo5] : (f16)0.0f;
                    const int gB = gb * 32 + c * 16 + (j & 3) + 8 * (j >> 2) + 4 * hi5;
                    const f16 bv = (lo5 < 25) ? (f16)(Y[lo5 * G_TOT + gB] * qw[gB]) : (f16)0.0f;
                    if (c == 0) { a1c0[j] = av; b2c0[j] = bv; }
                    else        { a1c1[j] = av; b2c1[j] = bv; }
                }
            body(a1c0, a1c1, b2c0, b2c1);
        }
    }

    // ---- CO reduce: 4-stage serialized across waves (deterministic)
    __syncthreads();
    for (int w = 0; w < 4; ++w) {
        if (wid == w) {
#pragma unroll
            for (int vt = 0; vt < 3; ++vt)
#pragma unroll
                for (int r = 0; r < 16; ++r) {
                    const int row = vt * 32 + (r & 3) + 8 * (r >> 2) + 4 * hi5;
                    if (w == 0) cob[row * CSTR + lo5] = coacc[vt][r];
                    else        cob[row * CSTR + lo5] += coacc[vt][r];
                }
        }
        __syncthreads();
    }

    // ---- epilogue (16x16x32 MFMA): wave v=wid<3: out = W_l^T x co
    if (wid < 3) {
        const int v = wid;
        const float* Wop = Wouts + p * 5120;
        float* outp = out + (n * 96 + p * 32) * 75 + v * 25;
        const int k0s[5] = {0, 1, 4, 9, 16};
        const int kws[5] = {1, 3, 5, 7, 9};
#pragma unroll
        for (int l = 0; l < 5; ++l) {
            const int k0 = k0s[l], kw = kws[l];
            v8h Bf;
            const int kk = (llo < kw) ? (k0 + llo) : k0;
#pragma unroll
            for (int j = 0; j < 8; ++j) {
                const int a = (j < 4) ? (lhi * 4 + j) : (16 + lhi * 4 + (j - 4));
                const float bv = (llo < kw) ? cob[(v * 32 + a) * CSTR + kk] : 0.0f;
                Bf[j] = (f16)bv;
            }
#pragma unroll
            for (int bt = 0; bt < 2; ++bt) {
                v8h Af;
#pragma unroll
                for (int j = 0; j < 8; ++j) {
                    const int a = (j < 4) ? (lhi * 4 + j) : (16 + lhi * 4 + (j - 4));
                    Af[j] = (f16)Wop[l * 1024 + a * 32 + bt * 16 + llo];
                }
                v4f D = __builtin_amdgcn_mfma_f32_16x16x32_f16(Af, Bf, zero4, 0, 0, 0);
                if (llo < kw) {
#pragma unroll
                    for (int jj = 0; jj < 4; ++jj)
                        outp[(bt * 16 + lhi * 4 + jj) * 75 + k0 + llo] = D[jj];
                }
            }
        }
    }
}

extern "C" void kernel_launch(void* const* d_in, const int* in_sizes, int n_in,
                              void* d_out, int out_size, void* d_ws, size_t ws_size,
                              hipStream_t stream) {
    const float* x1 = (const float*)d_in[0];
    const float* x2 = (const float*)d_in[1];
    const float* W1s = (const float*)d_in[2];
    const float* W2s = (const float*)d_in[3];
    const float* Wouts = (const float*)d_in[4];
    const float* Y = (const float*)d_in[5];
    const float* qw = (const float*)d_in[6];
    float* out = (float*)d_out;

    f16* A1buf = (f16*)d_ws;
    f16* B2buf = (f16*)((char*)d_ws + 129024);

    if (ws_size >= 258048) {
        vg_prep<<<NGB32, 64, 0, stream>>>(Y, qw, A1buf, B2buf);
        vg_main<true><<<1536, 256, 0, stream>>>(x1, x2, W1s, W2s, Wouts, Y, qw,
                                                A1buf, B2buf, out);
    } else {
        vg_main<false><<<1536, 256, 0, stream>>>(x1, x2, W1s, W2s, Wouts, Y, qw,
                                                 nullptr, nullptr, out);
    }
}